// Round 1
// baseline (1390.608 us; speedup 1.0000x reference)
//
#include <hip/hip_runtime.h>

// 2x2 mean-pool (kernel-weighted), stride 2.
// x: (B=16, C=64, H=512, W=512) fp32 -> out: (16, 64, 256, 256) fp32
// Memory-bound streaming kernel: 1 GiB in + 0.25 GiB out.
// One thread produces 4 consecutive output columns:
//   reads 2 rows x 8 input cols (four float4 loads), writes one float4.

constexpr int INW  = 512;   // input width
constexpr int INH  = 512;   // input height
constexpr int OUTW = 256;
constexpr int OUTH = 256;

__global__ __launch_bounds__(256)
void pool2x2_kernel(const float* __restrict__ x,
                    const float* __restrict__ kern,
                    float* __restrict__ out,
                    int total_groups) {
    int g = blockIdx.x * 256 + threadIdx.x;
    if (g >= total_groups) return;

    // Uniform-address kernel weights -> scalar loads, L1-resident.
    const float k00 = kern[0], k01 = kern[1], k10 = kern[2], k11 = kern[3];

    int cg    = g & 63;        // which group of 4 output cols (OUTW/4 = 64)
    int row   = g >> 6;        // flattened (plane, oh)
    int oh    = row & (OUTH - 1);
    int plane = row >> 8;      // b*C + c, in [0, 1024)

    const float* r0 = x + (size_t)plane * (INW * INH) + (size_t)(2 * oh) * INW + cg * 8;
    const float* r1 = r0 + INW;

    float4 a0 = *(const float4*)(r0);
    float4 a1 = *(const float4*)(r0 + 4);
    float4 b0 = *(const float4*)(r1);
    float4 b1 = *(const float4*)(r1 + 4);

    float4 o;
    o.x = k00 * a0.x + k01 * a0.y + k10 * b0.x + k11 * b0.y;
    o.y = k00 * a0.z + k01 * a0.w + k10 * b0.z + k11 * b0.w;
    o.z = k00 * a1.x + k01 * a1.y + k10 * b1.x + k11 * b1.y;
    o.w = k00 * a1.z + k01 * a1.w + k10 * b1.z + k11 * b1.w;

    *(float4*)(out + (size_t)row * OUTW + cg * 4) = o;
}

extern "C" void kernel_launch(void* const* d_in, const int* in_sizes, int n_in,
                              void* d_out, int out_size, void* d_ws, size_t ws_size,
                              hipStream_t stream) {
    const float* x    = (const float*)d_in[0];
    const float* kern = (const float*)d_in[1];
    float*       out  = (float*)d_out;

    // total output elements / 4 per thread
    int total_groups = out_size / 4;            // 67,108,864 / 4 = 16,777,216
    int blocks = (total_groups + 255) / 256;    // 65,536
    pool2x2_kernel<<<blocks, 256, 0, stream>>>(x, kern, out, total_groups);
}